// Round 11
// baseline (398.494 us; speedup 1.0000x reference)
//
#include <hip/hip_runtime.h>
#include <math.h>

typedef short short8 __attribute__((ext_vector_type(8)));
typedef float f32x4 __attribute__((ext_vector_type(4)));
typedef unsigned short us4 __attribute__((ext_vector_type(4)));
typedef unsigned short u16;
typedef unsigned int u32;

#define GAS __attribute__((address_space(1)))
#define LAS __attribute__((address_space(3)))

static __device__ __forceinline__ u16 f2bf(float f) {
    union { float f; u32 u; } v; v.f = f;
    u32 r = v.u + 0x7FFFu + ((v.u >> 16) & 1u);
    return (u16)(r >> 16);
}

static __device__ __forceinline__ u32 pk2(float a, float b) {
    return (u32)f2bf(a) | ((u32)f2bf(b) << 16);
}

static __device__ __forceinline__ float bf2f(u16 h) {
    union { u32 u; float f; } v; v.u = ((u32)h) << 16;
    return v.f;
}

// overflow-safe fast tanh
static __device__ __forceinline__ float ftanh(float v) {
    float t = __expf(-2.0f * fabsf(v));
    float r = (1.0f - t) / (1.0f + t);
    return copysignf(r, v);
}

static __device__ __forceinline__ void gll16(const void* g, void* l) {
    __builtin_amdgcn_global_load_lds((const GAS void*)g, (LAS void*)l, 16, 0, 0);
}

// ---------- cvt: x rows (+norms), W1, W_mlp all in one launch ----------
__global__ __launch_bounds__(256) void k_cvt_x(const float* __restrict__ x,
                                               u16* __restrict__ xb,
                                               float* __restrict__ xinv,
                                               const float* __restrict__ W1,
                                               u16* __restrict__ w1b,
                                               const float* __restrict__ Wm,
                                               u16* __restrict__ wmb) {
    const int bid = blockIdx.x, t = threadIdx.x;
    if (bid >= 17408) {  // W_mlp: 65536 blocks x 1024 elems
        const size_t i = (size_t)(bid - 17408) * 256 + t;
        const f32x4 v = *(const f32x4*)(Wm + 4 * i);
        u32* dst = (u32*)(wmb + 4 * i);
        dst[0] = pk2(v.x, v.y); dst[1] = pk2(v.z, v.w);
        return;
    }
    if (bid >= 16384) {  // W1: 1024 blocks
        const size_t i = (size_t)(bid - 16384) * 256 + t;
        const f32x4 v = *(const f32x4*)(W1 + 4 * i);
        u32* dst = (u32*)(w1b + 4 * i);
        dst[0] = pk2(v.x, v.y); dst[1] = pk2(v.z, v.w);
        return;
    }
    const int row = bid;
    const f32x4 v = *(const f32x4*)(x + (size_t)row * 1024 + 4 * t);
    u32* dst = (u32*)(xb + (size_t)row * 1024 + 4 * t);
    dst[0] = pk2(v.x, v.y); dst[1] = pk2(v.z, v.w);
    float s = v.x * v.x + v.y * v.y + v.z * v.z + v.w * v.w;
#pragma unroll
    for (int off = 1; off < 64; off <<= 1) s += __shfl_xor(s, off, 64);
    __shared__ float red[4];
    if ((t & 63) == 0) red[t >> 6] = s;
    __syncthreads();
    if (t == 0)
        xinv[row] = 1.0f / fmaxf(sqrtf(red[0] + red[1] + red[2] + red[3]), 1e-12f);
}

// ================= deep-prefetch 4-phase GEMM machinery =================
#define MFMA16(a, b, c) __builtin_amdgcn_mfma_f32_16x16x32_bf16(a, b, c, 0, 0, 0)
#define SBAR() __builtin_amdgcn_s_barrier()
#define SCHED0() __builtin_amdgcn_sched_barrier(0)
#define VMW6 asm volatile("s_waitcnt vmcnt(6)" ::: "memory")
#define VMW4 asm volatile("s_waitcnt vmcnt(4)" ::: "memory")
#define VMW2 asm volatile("s_waitcnt vmcnt(2)" ::: "memory")
#define VMW0 asm volatile("s_waitcnt vmcnt(0)" ::: "memory")
#define VMNOP do {} while (0)

// One K-tile (BK=64) = 4 phases; 2 gll16/phase; uniform vmcnt(6) (see slot algebra
// in commit notes): every phase-end wait retires exactly the 2 loads issued 4
// phases earlier -> 3-phase (~2400cy) flight per slot, > HBM latency.
// Slot issue schedule: ph0 Ah0(T+1), ph1 Bh1(T+1), ph2 Ah1(T+1), ph3 Bh0(T+2)->lbw.
#define DO_TILE(I0, I1, I2, I3, W0, W1M, W2, W3)                              \
  do {                                                                        \
    short8 Af[4][2], Bf0[2][2], Bf1[2][2];                                    \
    /* ph0: rd Ah0(mf0-3) + Bh0(nf0-1) */                                     \
    _Pragma("unroll") for (int m = 0; m < 4; ++m) {                           \
      Af[m][0] = *(const short8*)(la + rpA[m] + sw0);                         \
      Af[m][1] = *(const short8*)(la + rpA[m] + sw1);                         \
    }                                                                         \
    _Pragma("unroll") for (int n = 0; n < 2; ++n) {                           \
      Bf0[n][0] = *(const short8*)(lb + rpB[n] + sw0);                        \
      Bf0[n][1] = *(const short8*)(lb + rpB[n] + sw1);                        \
    }                                                                         \
    if (I0) { gll16(AG + (saO00 + knxa), danext + ldst);                      \
              gll16(AG + (saO01 + knxa), danext + 4096 + ldst); }             \
    SBAR(); SCHED0();                                                         \
    __builtin_amdgcn_s_setprio(1);                                            \
    _Pragma("unroll") for (int k = 0; k < 2; ++k)                             \
      _Pragma("unroll") for (int m = 0; m < 4; ++m)                           \
        _Pragma("unroll") for (int n = 0; n < 2; ++n)                         \
          acc[m][n] = MFMA16(Af[m][k], Bf0[n][k], acc[m][n]);                 \
    __builtin_amdgcn_s_setprio(0); SCHED0(); W0; SBAR();                      \
    /* ph1: rd Bh1(nf2-3) */                                                  \
    _Pragma("unroll") for (int n = 0; n < 2; ++n) {                           \
      Bf1[n][0] = *(const short8*)(lb + rpB[n + 2] + sw0);                    \
      Bf1[n][1] = *(const short8*)(lb + rpB[n + 2] + sw1);                    \
    }                                                                         \
    if (I1) { gll16(BG + (sbO10 + knxa), dbnext + 8192 + ldst);               \
              gll16(BG + (sbO11 + knxa), dbnext + 8192 + 4096 + ldst); }      \
    SBAR(); SCHED0();                                                         \
    __builtin_amdgcn_s_setprio(1);                                            \
    _Pragma("unroll") for (int k = 0; k < 2; ++k)                             \
      _Pragma("unroll") for (int m = 0; m < 4; ++m)                           \
        _Pragma("unroll") for (int n = 0; n < 2; ++n)                         \
          acc[m][n + 2] = MFMA16(Af[m][k], Bf1[n][k], acc[m][n + 2]);         \
    __builtin_amdgcn_s_setprio(0); SCHED0(); W1M; SBAR();                     \
    /* ph2: rd Ah1(mf4-7) */                                                  \
    _Pragma("unroll") for (int m = 0; m < 4; ++m) {                           \
      Af[m][0] = *(const short8*)(la + rpA[m + 4] + sw0);                     \
      Af[m][1] = *(const short8*)(la + rpA[m + 4] + sw1);                     \
    }                                                                         \
    if (I2) { gll16(AG + (saO10 + knxa), danext + 8192 + ldst);               \
              gll16(AG + (saO11 + knxa), danext + 8192 + 4096 + ldst); }      \
    SBAR(); SCHED0();                                                         \
    __builtin_amdgcn_s_setprio(1);                                            \
    _Pragma("unroll") for (int k = 0; k < 2; ++k)                             \
      _Pragma("unroll") for (int m = 0; m < 4; ++m)                           \
        _Pragma("unroll") for (int n = 0; n < 2; ++n)                         \
          acc[m + 4][n] = MFMA16(Af[m][k], Bf0[n][k], acc[m + 4][n]);         \
    __builtin_amdgcn_s_setprio(0); SCHED0(); W2; SBAR();                      \
    /* ph3: no reads; issue Bh0(T+2) into CURRENT B buffer (read done @ph0) */ \
    if (I3) { gll16(BG + (sbO00 + knxb), lbw + ldst);                         \
              gll16(BG + (sbO01 + knxb), lbw + 4096 + ldst); }                \
    SBAR(); SCHED0();                                                         \
    __builtin_amdgcn_s_setprio(1);                                            \
    _Pragma("unroll") for (int k = 0; k < 2; ++k)                             \
      _Pragma("unroll") for (int m = 0; m < 4; ++m)                           \
        _Pragma("unroll") for (int n = 0; n < 2; ++n)                         \
          acc[m + 4][n + 2] = MFMA16(Af[m][k], Bf1[n][k], acc[m + 4][n + 2]); \
    __builtin_amdgcn_s_setprio(0); SCHED0(); W3; SBAR();                      \
  } while (0)

// shared prologue: T0 full (4 half-tiles, consumption order) + Bh0(T1); retire T0's ph0 slots
#define GEMM_PROLOGUE()                                                       \
  do {                                                                        \
    gll16(AG + saO00, &LsA[0][0] + ldst);                                     \
    gll16(AG + saO01, &LsA[0][0] + 4096 + ldst);                              \
    gll16(BG + sbO00, &LsB[0][0] + ldst);                                     \
    gll16(BG + sbO01, &LsB[0][0] + 4096 + ldst);                              \
    gll16(BG + sbO10, &LsB[0][0] + 8192 + ldst);                              \
    gll16(BG + sbO11, &LsB[0][0] + 8192 + 4096 + ldst);                       \
    gll16(AG + saO10, &LsA[0][0] + 8192 + ldst);                              \
    gll16(AG + saO11, &LsA[0][0] + 8192 + 4096 + ldst);                       \
    gll16(BG + sbO00 + 64, &LsB[1][0] + ldst);                                \
    gll16(BG + sbO01 + 64, &LsB[1][0] + 4096 + ldst);                         \
    VMW6; SBAR();                                                             \
  } while (0)

// ================= GEMM1: wg = x_bf @ W1_bf^T + b1 =================
__global__ __launch_bounds__(512, 2) void k_gemm1_8ph(const u16* __restrict__ AG,
                                                      const u16* __restrict__ BG,
                                                      const float* __restrict__ bias,
                                                      u16* __restrict__ C,
                                                      float* __restrict__ wgn2) {
    __shared__ __align__(16) u16 LsA[2][16384];
    __shared__ __align__(16) u16 LsB[2][16384];
    const int K = 1024, NT = 16;
    const int lin = blockIdx.x;
    const int w = (lin & 7) * 32 + (lin >> 3);
    const int n0 = (w & 3) * 256;
    const int m0 = (w >> 2) * 256;

    const int tid = threadIdx.x, wave = tid >> 6, lane = tid & 63;
    const int lr = lane & 15, kq = lane >> 4;
    const int wr = wave >> 2, wc = wave & 3;

    const int trow = tid >> 3;
    const u32 swsrc = (u32)(((tid & 7) ^ (trow & 7)) * 8);
    const u32 saO00 = (u32)(m0 + 0 + trow) * (u32)K + swsrc;
    const u32 saO01 = (u32)(m0 + 128 + trow) * (u32)K + swsrc;
    const u32 saO10 = (u32)(m0 + 64 + trow) * (u32)K + swsrc;
    const u32 saO11 = (u32)(m0 + 192 + trow) * (u32)K + swsrc;
    const int q0 = trow, q1 = 64 + trow;
    const u32 sbO00 = (u32)(n0 + (q0 >> 5) * 64 + (q0 & 31)) * (u32)K + swsrc;
    const u32 sbO01 = (u32)(n0 + (q1 >> 5) * 64 + (q1 & 31)) * (u32)K + swsrc;
    const u32 sbO10 = (u32)(n0 + (q0 >> 5) * 64 + 32 + (q0 & 31)) * (u32)K + swsrc;
    const u32 sbO11 = (u32)(n0 + (q1 >> 5) * 64 + 32 + (q1 & 31)) * (u32)K + swsrc;
    const u32 ldst = (u32)wave * 512;

    int rpA[8], rpB[4];
#pragma unroll
    for (int mf = 0; mf < 8; ++mf)
        rpA[mf] = ((mf >> 2) * 128 + wr * 64 + (mf & 3) * 16 + lr) << 6;
#pragma unroll
    for (int nf = 0; nf < 4; ++nf)
        rpB[nf] = ((nf >> 1) * 128 + wc * 32 + (nf & 1) * 16 + lr) << 6;
    const int sw0 = ((0 + kq) ^ (lr & 7)) * 8;
    const int sw1 = ((4 + kq) ^ (lr & 7)) * 8;

    f32x4 acc[8][4] = {};

    GEMM_PROLOGUE();

    int cur = 0;
    for (int T = 0; T < NT - 2; ++T) {
        const u16* la = &LsA[cur][0];
        const u16* lb = &LsB[cur][0];
        u16* danext = &LsA[cur ^ 1][0];
        u16* dbnext = &LsB[cur ^ 1][0];
        u16* lbw = &LsB[cur][0];
        const u32 knxa = (u32)(T + 1) * 64;
        const u32 knxb = (u32)(T + 2) * 64;
        DO_TILE(1, 1, 1, 1, VMW6, VMW6, VMW6, VMW6);
        cur ^= 1;
    }
    {   // T = NT-2: no ph3 issue; drain to 4
        const u16* la = &LsA[cur][0];
        const u16* lb = &LsB[cur][0];
        u16* danext = &LsA[cur ^ 1][0];
        u16* dbnext = &LsB[cur ^ 1][0];
        u16* lbw = &LsB[cur][0];
        const u32 knxa = (u32)(NT - 1) * 64, knxb = 0;
        (void)knxb;
        DO_TILE(1, 1, 1, 0, VMW6, VMW6, VMW6, VMW4);
        cur ^= 1;
    }
    {   // T = NT-1: no issues; drain 2 -> 0
        const u16* la = &LsA[cur][0];
        const u16* lb = &LsB[cur][0];
        u16* danext = &LsA[cur ^ 1][0];
        u16* dbnext = &LsB[cur ^ 1][0];
        u16* lbw = &LsB[cur][0];
        const u32 knxa = 0, knxb = 0;
        (void)danext; (void)dbnext; (void)lbw; (void)knxa; (void)knxb;
        DO_TILE(0, 0, 0, 0, VMW2, VMW0, VMNOP, VMNOP);
    }

    const int col0 = n0 + wc * 64;
    const int row0 = m0 + wr * 128;
    float bcol[4];
#pragma unroll
    for (int nf = 0; nf < 4; ++nf) bcol[nf] = bias[col0 + nf * 16 + lr];
#pragma unroll
    for (int mf = 0; mf < 8; ++mf) {
#pragma unroll
        for (int r = 0; r < 4; ++r) {
            const int row = row0 + mf * 16 + kq * 4 + r;
            float nrm = 0.f;
#pragma unroll
            for (int nf = 0; nf < 4; ++nf) {
                float v = acc[mf][nf][r] + bcol[nf];
                C[(size_t)row * 1024 + col0 + nf * 16 + lr] = f2bf(v);
                nrm += v * v;
            }
#pragma unroll
            for (int off = 1; off < 16; off <<= 1) nrm += __shfl_xor(nrm, off, 64);
            if (lr == 0) atomicAdd(&wgn2[row], nrm);
        }
    }
}

// ================= GEMM2: part[z] = attn_bf @ wm_bf^T (split-K=4) =================
__global__ __launch_bounds__(512, 2) void k_gemm2_8ph(const u16* __restrict__ AG,
                                                      const u16* __restrict__ BG,
                                                      u16* __restrict__ part) {
    __shared__ __align__(16) u16 LsA[2][16384];
    __shared__ __align__(16) u16 LsB[2][16384];
    const int K = 16384, NT = 64;
    const int lin = blockIdx.x;
    const int w = (lin & 7) * 32 + (lin >> 3);
    const int m0 = (w & 3) * 256;
    const int z = (w >> 2) & 3;
    const int n0 = (w >> 4) * 256;
    const int kbeg = z * 4096;

    const int tid = threadIdx.x, wave = tid >> 6, lane = tid & 63;
    const int lr = lane & 15, kq = lane >> 4;
    const int wr = wave >> 2, wc = wave & 3;

    const int trow = tid >> 3;
    const u32 swsrc = (u32)(((tid & 7) ^ (trow & 7)) * 8);
    const u32 saO00 = (u32)(m0 + 0 + trow) * (u32)K + (u32)kbeg + swsrc;
    const u32 saO01 = (u32)(m0 + 128 + trow) * (u32)K + (u32)kbeg + swsrc;
    const u32 saO10 = (u32)(m0 + 64 + trow) * (u32)K + (u32)kbeg + swsrc;
    const u32 saO11 = (u32)(m0 + 192 + trow) * (u32)K + (u32)kbeg + swsrc;
    const int q0 = trow, q1 = 64 + trow;
    const u32 sbO00 = (u32)(n0 + (q0 >> 5) * 64 + (q0 & 31)) * (u32)K + (u32)kbeg + swsrc;
    const u32 sbO01 = (u32)(n0 + (q1 >> 5) * 64 + (q1 & 31)) * (u32)K + (u32)kbeg + swsrc;
    const u32 sbO10 = (u32)(n0 + (q0 >> 5) * 64 + 32 + (q0 & 31)) * (u32)K + (u32)kbeg + swsrc;
    const u32 sbO11 = (u32)(n0 + (q1 >> 5) * 64 + 32 + (q1 & 31)) * (u32)K + (u32)kbeg + swsrc;
    const u32 ldst = (u32)wave * 512;

    int rpA[8], rpB[4];
#pragma unroll
    for (int mf = 0; mf < 8; ++mf)
        rpA[mf] = ((mf >> 2) * 128 + wr * 64 + (mf & 3) * 16 + lr) << 6;
#pragma unroll
    for (int nf = 0; nf < 4; ++nf)
        rpB[nf] = ((nf >> 1) * 128 + wc * 32 + (nf & 1) * 16 + lr) << 6;
    const int sw0 = ((0 + kq) ^ (lr & 7)) * 8;
    const int sw1 = ((4 + kq) ^ (lr & 7)) * 8;

    f32x4 acc[8][4] = {};

    GEMM_PROLOGUE();

    int cur = 0;
    for (int T = 0; T < NT - 2; ++T) {
        const u16* la = &LsA[cur][0];
        const u16* lb = &LsB[cur][0];
        u16* danext = &LsA[cur ^ 1][0];
        u16* dbnext = &LsB[cur ^ 1][0];
        u16* lbw = &LsB[cur][0];
        const u32 knxa = (u32)(T + 1) * 64;
        const u32 knxb = (u32)(T + 2) * 64;
        DO_TILE(1, 1, 1, 1, VMW6, VMW6, VMW6, VMW6);
        cur ^= 1;
    }
    {   // T = NT-2
        const u16* la = &LsA[cur][0];
        const u16* lb = &LsB[cur][0];
        u16* danext = &LsA[cur ^ 1][0];
        u16* dbnext = &LsB[cur ^ 1][0];
        u16* lbw = &LsB[cur][0];
        const u32 knxa = (u32)(NT - 1) * 64, knxb = 0;
        (void)knxb;
        DO_TILE(1, 1, 1, 0, VMW6, VMW6, VMW6, VMW4);
        cur ^= 1;
    }
    {   // T = NT-1
        const u16* la = &LsA[cur][0];
        const u16* lb = &LsB[cur][0];
        u16* danext = &LsA[cur ^ 1][0];
        u16* dbnext = &LsB[cur ^ 1][0];
        u16* lbw = &LsB[cur][0];
        const u32 knxa = 0, knxb = 0;
        (void)danext; (void)dbnext; (void)lbw; (void)knxa; (void)knxb;
        DO_TILE(0, 0, 0, 0, VMW2, VMW0, VMNOP, VMNOP);
    }

    u16* po = part + (size_t)z * 4194304ull;
    const int col0 = n0 + wc * 64;
    const int row0 = m0 + wr * 128;
#pragma unroll
    for (int mf = 0; mf < 8; ++mf)
#pragma unroll
        for (int r = 0; r < 4; ++r) {
            const int row = row0 + mf * 16 + kq * 4 + r;
#pragma unroll
            for (int nf = 0; nf < 4; ++nf)
                po[(size_t)row * 4096 + col0 + nf * 16 + lr] = f2bf(acc[mf][nf][r]);
        }
}

// ---------- merged per-batch graph algebra + attention readout ----------
__global__ __launch_bounds__(256) void k_batch_attn(const u16* xb,
                                                    const u16* __restrict__ wgb,
                                                    const float* __restrict__ xinv,
                                                    const float* __restrict__ wgn2,
                                                    const float* __restrict__ matrix,
                                                    const float* __restrict__ a_param,
                                                    float* __restrict__ e2_out,
                                                    float* __restrict__ m_out,
                                                    u16* attn_bf) {
    const int b = blockIdx.x, tid = threadIdx.x;
    const int wave = tid >> 6, lane = tid & 63;
    const int j = lane & 15, ig = (lane >> 4) * 4;

    __shared__ float qred[4][64][4];
    __shared__ float esm_l[16 * 17];
    __shared__ float fi_l[16 * 17];
    __shared__ float e2_l[16 * 17];
    __shared__ float m_l[256];
    __shared__ float as_l[256];
    __shared__ u16 xsh[16][256];

    {
        const size_t roff = (size_t)(b * 16 + j) * 1024 + (lane >> 4) * 8 + wave * 256;
        f32x4 acc0 = {}, acc1 = {};
#pragma unroll
        for (int kt = 0; kt < 256; kt += 64) {
            short8 xa0 = *(const short8*)(xb + roff + kt);
            short8 wa0 = *(const short8*)(wgb + roff + kt);
            short8 xa1 = *(const short8*)(xb + roff + kt + 32);
            short8 wa1 = *(const short8*)(wgb + roff + kt + 32);
            acc0 = __builtin_amdgcn_mfma_f32_16x16x32_bf16(xa0, wa0, acc0, 0, 0, 0);
            acc1 = __builtin_amdgcn_mfma_f32_16x16x32_bf16(xa1, wa1, acc1, 0, 0, 0);
        }
#pragma unroll
        for (int r = 0; r < 4; ++r) qred[wave][lane][r] = acc0[r] + acc1[r];
    }
    __syncthreads();

    if (tid < 64) {
        const int l = tid;
        const float inw = 1.0f / fmaxf(sqrtf(wgn2[b * 16 + j]), 1e-12f);
        const float boost = 1.0f + a_param[0];
        float e[4];
#pragma unroll
        for (int r = 0; r < 4; ++r) {
            const int i = ig + r;
            float v = (qred[0][l][r] + qred[1][l][r] + qred[2][l][r] + qred[3][l][r]) *
                      xinv[b * 16 + i] * inw;
            if (i == j) v *= boost;
            e[r] = v;
            as_l[i * 16 + j] = v;
        }
        float mx = fmaxf(fmaxf(e[0], e[1]), fmaxf(e[2], e[3]));
        mx = fmaxf(mx, __shfl_xor(mx, 16, 64));
        mx = fmaxf(mx, __shfl_xor(mx, 32, 64));
        float p[4], s = 0.f;
#pragma unroll
        for (int r = 0; r < 4; ++r) { p[r] = __expf(e[r] - mx); s += p[r]; }
        s += __shfl_xor(s, 16, 64);
        s += __shfl_xor(s, 32, 64);
        const float invs = 1.0f / s;
#pragma unroll
        for (int r = 0; r < 4; ++r) esm_l[(ig + r) * 17 + j] = p[r] * invs;
        const f32x4 mv = *(const f32x4*)(matrix + (size_t)b * 256 + 4 * l);
        *(f32x4*)(m_l + 4 * l) = mv;
        *(f32x4*)(m_out + (size_t)b * 256 + 4 * l) = mv;
    }
    __syncthreads();
    if (tid < 64) {
        float fi[4] = {0, 0, 0, 0};
#pragma unroll
        for (int t = 0; t < 16; ++t) {
            const float mk = m_l[t * 16 + j];
#pragma unroll
            for (int r = 0; r < 4; ++r) fi[r] += esm_l[(ig + r) * 17 + t] * mk;
        }
#pragma unroll
        for (int r = 0; r < 4; ++r) fi_l[(ig + r) * 17 + j] = fi[r];
    }
    __syncthreads();
    if (tid < 64) {
        float e2v[4] = {0, 0, 0, 0};
#pragma unroll
        for (int kk = 0; kk < 16; ++kk) {
            const float wgt = esm_l[j * 17 + kk] * m_l[kk * 16 + kk];
#pragma unroll
            for (int r = 0; r < 4; ++r) e2v[r] += fi_l[(ig + r) * 17 + kk] * wgt;
        }
#pragma unroll
        for (int r = 0; r < 4; ++r) e2_l[(ig + r) * 17 + j] = e2v[r];
    }
    __syncthreads();
    if (tid < 64) {
#pragma unroll
        for (int r = 0; r < 4; ++r) {
            const int i = ig + r;
            e2_out[(size_t)b * 256 + i * 16 + j] =
                0.5f * (e2_l[i * 17 + j] + e2_l[j * 17 + i]);
        }
    }

    const int srow = tid >> 4;
    const int scol = (tid & 15) * 16;
    for (int ch = 0; ch < 4; ++ch) {
        __syncthreads();
        const u16* src = xb + ((size_t)b * 16 + srow) * 1024 + ch * 256 + scol;
        *(short8*)&xsh[srow][scol] = *(const short8*)src;
        *(short8*)&xsh[srow][scol + 8] = *(const short8*)(src + 8);
        __syncthreads();
        float accv[16] = {};
#pragma unroll
        for (int jj = 0; jj < 16; ++jj) {
            const float xv = bf2f(xsh[jj][tid]);
#pragma unroll
            for (int i = 0; i < 16; ++i) accv[i] = fmaf(as_l[jj * 16 + i], xv, accv[i]);
        }
#pragma unroll
        for (int i = 0; i < 16; ++i)
            attn_bf[((size_t)b * 16 + i) * 1024 + ch * 256 + tid] = f2bf(ftanh(accv[i]));
    }
}

// ---------- broadcast: out[b, rep, :] = sum_z part[z][b,:] + b_mlp ----------
__global__ __launch_bounds__(256) void k_bcast(const u16* __restrict__ p,
                                               const float* __restrict__ bias,
                                               float* __restrict__ out) {
    const size_t i = (size_t)blockIdx.x * 256 + threadIdx.x;
    const int o4 = (int)(i & 1023);
    const int b = (int)(i >> 14);
    const size_t src = (size_t)b * 4096 + (size_t)o4 * 4;
    f32x4 r = *(const f32x4*)(bias + (size_t)o4 * 4);
#pragma unroll
    for (int z = 0; z < 4; ++z) {
        us4 v = *(const us4*)(p + (size_t)z * 4194304ull + src);
        r.x += bf2f(v.x); r.y += bf2f(v.y); r.z += bf2f(v.z); r.w += bf2f(v.w);
    }
    *(f32x4*)(out + i * 4) = r;
}

extern "C" void kernel_launch(void* const* d_in, const int* in_sizes, int n_in,
                              void* d_out, int out_size, void* d_ws, size_t ws_size,
                              hipStream_t stream) {
    const float* x      = (const float*)d_in[0];
    const float* matrix = (const float*)d_in[1];
    const float* W1     = (const float*)d_in[2];
    const float* b1     = (const float*)d_in[3];
    const float* W_mlp  = (const float*)d_in[4];
    const float* b_mlp  = (const float*)d_in[5];
    const float* a_par  = (const float*)d_in[6];
    float* out = (float*)d_out;

    char* ws = (char*)d_ws;
    size_t off = 0;
    auto alloc = [&](size_t bytes) {
        char* p = ws + off;
        off += (bytes + 255) & ~(size_t)255;
        return p;
    };
    u16*   x_bf  = (u16*)alloc(16384ull * 1024 * 2);    // reused as attn_bf
    u16*   wg_bf = (u16*)alloc(16384ull * 1024 * 2);    // reused as GEMM2 bf16 partials
    u16*   w1_bf = (u16*)alloc(1024ull * 1024 * 2);
    u16*   wm_bf = (u16*)alloc(4096ull * 16384 * 2);
    float* xinv  = (float*)alloc(16384ull * 4);
    float* wgn2  = (float*)alloc(16384ull * 4);
    u16*   attn_bf = x_bf;
    u16*   part    = wg_bf;
    float* e2_out = out + 67108864ull;
    float* m_out  = out + 67371008ull;

    hipMemsetAsync(wgn2, 0, 16384 * 4, stream);
    k_cvt_x<<<82944, 256, 0, stream>>>(x, x_bf, xinv, W1, w1_bf, W_mlp, wm_bf);
    k_gemm1_8ph<<<256, 512, 0, stream>>>(x_bf, w1_bf, b1, wg_bf, wgn2);
    k_batch_attn<<<1024, 256, 0, stream>>>(x_bf, wg_bf, xinv, wgn2, matrix, a_par,
                                           e2_out, m_out, attn_bf);
    k_gemm2_8ph<<<256, 512, 0, stream>>>(attn_bf, wm_bf, part);
    k_bcast<<<65536, 256, 0, stream>>>(part, b_mlp, out);
}

// Round 12
// 339.320 us; speedup vs baseline: 1.1744x; 1.1744x over previous
//
#include <hip/hip_runtime.h>
#include <math.h>

typedef short short8 __attribute__((ext_vector_type(8)));
typedef float f32x4 __attribute__((ext_vector_type(4)));
typedef unsigned short us4 __attribute__((ext_vector_type(4)));
typedef unsigned short u16;
typedef unsigned int u32;

#define GAS __attribute__((address_space(1)))
#define LAS __attribute__((address_space(3)))

static __device__ __forceinline__ u16 f2bf(float f) {
    union { float f; u32 u; } v; v.f = f;
    u32 r = v.u + 0x7FFFu + ((v.u >> 16) & 1u);
    return (u16)(r >> 16);
}

static __device__ __forceinline__ u32 pk2(float a, float b) {
    return (u32)f2bf(a) | ((u32)f2bf(b) << 16);
}

static __device__ __forceinline__ u32 cvtpk(float lo, float hi) {
    u32 r;
    asm("v_cvt_pk_bf16_f32 %0, %1, %2" : "=v"(r) : "v"(lo), "v"(hi));
    return r;
}

static __device__ __forceinline__ float bf2f(u16 h) {
    union { u32 u; float f; } v; v.u = ((u32)h) << 16;
    return v.f;
}

static __device__ __forceinline__ float ftanh(float v) {
    float t = __expf(-2.0f * fabsf(v));
    float r = (1.0f - t) / (1.0f + t);
    return copysignf(r, v);
}

static __device__ __forceinline__ void gll16(const void* g, void* l) {
    __builtin_amdgcn_global_load_lds((const GAS void*)g, (LAS void*)l, 16, 0, 0);
}

// ---------- cvt: x rows (+norms) and W1 ----------
__global__ __launch_bounds__(256) void k_cvt_x(const float* __restrict__ x,
                                               u16* __restrict__ xb,
                                               float* __restrict__ xinv,
                                               const float* __restrict__ W1,
                                               u16* __restrict__ w1b) {
    const int bid = blockIdx.x, t = threadIdx.x;
    if (bid >= 16384) {
        const size_t i = (size_t)(bid - 16384) * 256 + t;
        const f32x4 v = *(const f32x4*)(W1 + 4 * i);
        u32* dst = (u32*)(w1b + 4 * i);
        dst[0] = pk2(v.x, v.y); dst[1] = pk2(v.z, v.w);
        return;
    }
    const int row = bid;
    const f32x4 v = *(const f32x4*)(x + (size_t)row * 1024 + 4 * t);
    u32* dst = (u32*)(xb + (size_t)row * 1024 + 4 * t);
    dst[0] = pk2(v.x, v.y); dst[1] = pk2(v.z, v.w);
    float s = v.x * v.x + v.y * v.y + v.z * v.z + v.w * v.w;
#pragma unroll
    for (int off = 1; off < 64; off <<= 1) s += __shfl_xor(s, off, 64);
    __shared__ float red[4];
    if ((t & 63) == 0) red[t >> 6] = s;
    __syncthreads();
    if (t == 0)
        xinv[row] = 1.0f / fmaxf(sqrtf(red[0] + red[1] + red[2] + red[3]), 1e-12f);
}

// ================= GEMM machinery =================
#define MFMA16(a, b, c) __builtin_amdgcn_mfma_f32_16x16x32_bf16(a, b, c, 0, 0, 0)
#define SBAR() __builtin_amdgcn_s_barrier()
#define SCHED0() __builtin_amdgcn_sched_barrier(0)
#define VMW6 asm volatile("s_waitcnt vmcnt(6)" ::: "memory")
#define VMW4 asm volatile("s_waitcnt vmcnt(4)" ::: "memory")
#define VMW2 asm volatile("s_waitcnt vmcnt(2)" ::: "memory")
#define VMW0 asm volatile("s_waitcnt vmcnt(0)" ::: "memory")
#define VMNOP do {} while (0)

// -------- GEMM1 tile (R11 schedule, bf16 A/B via gll16, uniform vmcnt(6)) --------
#define DO_TILE(I0, I1, I2, I3, W0, W1M, W2, W3)                              \
  do {                                                                        \
    short8 Af[4][2], Bf0[2][2], Bf1[2][2];                                    \
    _Pragma("unroll") for (int m = 0; m < 4; ++m) {                           \
      Af[m][0] = *(const short8*)(la + rpA[m] + sw0);                         \
      Af[m][1] = *(const short8*)(la + rpA[m] + sw1);                         \
    }                                                                         \
    _Pragma("unroll") for (int n = 0; n < 2; ++n) {                           \
      Bf0[n][0] = *(const short8*)(lb + rpB[n] + sw0);                        \
      Bf0[n][1] = *(const short8*)(lb + rpB[n] + sw1);                        \
    }                                                                         \
    if (I0) { gll16(AG + (saO00 + knxa), danext + ldst);                      \
              gll16(AG + (saO01 + knxa), danext + 4096 + ldst); }             \
    SBAR(); SCHED0();                                                         \
    __builtin_amdgcn_s_setprio(1);                                            \
    _Pragma("unroll") for (int k = 0; k < 2; ++k)                             \
      _Pragma("unroll") for (int m = 0; m < 4; ++m)                           \
        _Pragma("unroll") for (int n = 0; n < 2; ++n)                         \
          acc[m][n] = MFMA16(Af[m][k], Bf0[n][k], acc[m][n]);                 \
    __builtin_amdgcn_s_setprio(0); SCHED0(); W0; SBAR();                      \
    _Pragma("unroll") for (int n = 0; n < 2; ++n) {                           \
      Bf1[n][0] = *(const short8*)(lb + rpB[n + 2] + sw0);                    \
      Bf1[n][1] = *(const short8*)(lb + rpB[n + 2] + sw1);                    \
    }                                                                         \
    if (I1) { gll16(BG + (sbO10 + knxa), dbnext + 8192 + ldst);               \
              gll16(BG + (sbO11 + knxa), dbnext + 8192 + 4096 + ldst); }      \
    SBAR(); SCHED0();                                                         \
    __builtin_amdgcn_s_setprio(1);                                            \
    _Pragma("unroll") for (int k = 0; k < 2; ++k)                             \
      _Pragma("unroll") for (int m = 0; m < 4; ++m)                           \
        _Pragma("unroll") for (int n = 0; n < 2; ++n)                         \
          acc[m][n + 2] = MFMA16(Af[m][k], Bf1[n][k], acc[m][n + 2]);         \
    __builtin_amdgcn_s_setprio(0); SCHED0(); W1M; SBAR();                     \
    _Pragma("unroll") for (int m = 0; m < 4; ++m) {                           \
      Af[m][0] = *(const short8*)(la + rpA[m + 4] + sw0);                     \
      Af[m][1] = *(const short8*)(la + rpA[m + 4] + sw1);                     \
    }                                                                         \
    if (I2) { gll16(AG + (saO10 + knxa), danext + 8192 + ldst);               \
              gll16(AG + (saO11 + knxa), danext + 8192 + 4096 + ldst); }      \
    SBAR(); SCHED0();                                                         \
    __builtin_amdgcn_s_setprio(1);                                            \
    _Pragma("unroll") for (int k = 0; k < 2; ++k)                             \
      _Pragma("unroll") for (int m = 0; m < 4; ++m)                           \
        _Pragma("unroll") for (int n = 0; n < 2; ++n)                         \
          acc[m + 4][n] = MFMA16(Af[m][k], Bf0[n][k], acc[m + 4][n]);         \
    __builtin_amdgcn_s_setprio(0); SCHED0(); W2; SBAR();                      \
    if (I3) { gll16(BG + (sbO00 + knxb), lbw + ldst);                         \
              gll16(BG + (sbO01 + knxb), lbw + 4096 + ldst); }                \
    SBAR(); SCHED0();                                                         \
    __builtin_amdgcn_s_setprio(1);                                            \
    _Pragma("unroll") for (int k = 0; k < 2; ++k)                             \
      _Pragma("unroll") for (int m = 0; m < 4; ++m)                           \
        _Pragma("unroll") for (int n = 0; n < 2; ++n)                         \
          acc[m + 4][n + 2] = MFMA16(Af[m][k], Bf1[n][k], acc[m + 4][n + 2]); \
    __builtin_amdgcn_s_setprio(0); SCHED0(); W3; SBAR();                      \
  } while (0)

#define GEMM_PROLOGUE()                                                       \
  do {                                                                        \
    gll16(AG + saO00, &LsA[0][0] + ldst);                                     \
    gll16(AG + saO01, &LsA[0][0] + 4096 + ldst);                              \
    gll16(BG + sbO00, &LsB[0][0] + ldst);                                     \
    gll16(BG + sbO01, &LsB[0][0] + 4096 + ldst);                              \
    gll16(BG + sbO10, &LsB[0][0] + 8192 + ldst);                              \
    gll16(BG + sbO11, &LsB[0][0] + 8192 + 4096 + ldst);                       \
    gll16(AG + saO10, &LsA[0][0] + 8192 + ldst);                              \
    gll16(AG + saO11, &LsA[0][0] + 8192 + 4096 + ldst);                       \
    gll16(BG + sbO00 + 64, &LsB[1][0] + ldst);                                \
    gll16(BG + sbO01 + 64, &LsB[1][0] + 4096 + ldst);                         \
    VMW6; SBAR();                                                             \
  } while (0)

// ================= GEMM1: wg = x_bf @ W1_bf^T + b1 (unchanged from R11) =================
__global__ __launch_bounds__(512, 2) void k_gemm1_8ph(const u16* __restrict__ AG,
                                                      const u16* __restrict__ BG,
                                                      const float* __restrict__ bias,
                                                      u16* __restrict__ C,
                                                      float* __restrict__ wgn2) {
    __shared__ __align__(16) u16 LsA[2][16384];
    __shared__ __align__(16) u16 LsB[2][16384];
    const int K = 1024, NT = 16;
    const int lin = blockIdx.x;
    const int w = (lin & 7) * 32 + (lin >> 3);
    const int n0 = (w & 3) * 256;
    const int m0 = (w >> 2) * 256;

    const int tid = threadIdx.x, wave = tid >> 6, lane = tid & 63;
    const int lr = lane & 15, kq = lane >> 4;
    const int wr = wave >> 2, wc = wave & 3;

    const int trow = tid >> 3;
    const u32 swsrc = (u32)(((tid & 7) ^ (trow & 7)) * 8);
    const u32 saO00 = (u32)(m0 + 0 + trow) * (u32)K + swsrc;
    const u32 saO01 = (u32)(m0 + 128 + trow) * (u32)K + swsrc;
    const u32 saO10 = (u32)(m0 + 64 + trow) * (u32)K + swsrc;
    const u32 saO11 = (u32)(m0 + 192 + trow) * (u32)K + swsrc;
    const int q0 = trow, q1 = 64 + trow;
    const u32 sbO00 = (u32)(n0 + (q0 >> 5) * 64 + (q0 & 31)) * (u32)K + swsrc;
    const u32 sbO01 = (u32)(n0 + (q1 >> 5) * 64 + (q1 & 31)) * (u32)K + swsrc;
    const u32 sbO10 = (u32)(n0 + (q0 >> 5) * 64 + 32 + (q0 & 31)) * (u32)K + swsrc;
    const u32 sbO11 = (u32)(n0 + (q1 >> 5) * 64 + 32 + (q1 & 31)) * (u32)K + swsrc;
    const u32 ldst = (u32)wave * 512;

    int rpA[8], rpB[4];
#pragma unroll
    for (int mf = 0; mf < 8; ++mf)
        rpA[mf] = ((mf >> 2) * 128 + wr * 64 + (mf & 3) * 16 + lr) << 6;
#pragma unroll
    for (int nf = 0; nf < 4; ++nf)
        rpB[nf] = ((nf >> 1) * 128 + wc * 32 + (nf & 1) * 16 + lr) << 6;
    const int sw0 = ((0 + kq) ^ (lr & 7)) * 8;
    const int sw1 = ((4 + kq) ^ (lr & 7)) * 8;

    f32x4 acc[8][4] = {};

    GEMM_PROLOGUE();

    int cur = 0;
    for (int T = 0; T < NT - 2; ++T) {
        const u16* la = &LsA[cur][0];
        const u16* lb = &LsB[cur][0];
        u16* danext = &LsA[cur ^ 1][0];
        u16* dbnext = &LsB[cur ^ 1][0];
        u16* lbw = &LsB[cur][0];
        const u32 knxa = (u32)(T + 1) * 64;
        const u32 knxb = (u32)(T + 2) * 64;
        DO_TILE(1, 1, 1, 1, VMW6, VMW6, VMW6, VMW6);
        cur ^= 1;
    }
    {
        const u16* la = &LsA[cur][0];
        const u16* lb = &LsB[cur][0];
        u16* danext = &LsA[cur ^ 1][0];
        u16* dbnext = &LsB[cur ^ 1][0];
        u16* lbw = &LsB[cur][0];
        const u32 knxa = (u32)(NT - 1) * 64, knxb = 0;
        (void)knxb;
        DO_TILE(1, 1, 1, 0, VMW6, VMW6, VMW6, VMW4);
        cur ^= 1;
    }
    {
        const u16* la = &LsA[cur][0];
        const u16* lb = &LsB[cur][0];
        u16* danext = &LsA[cur ^ 1][0];
        u16* dbnext = &LsB[cur ^ 1][0];
        u16* lbw = &LsB[cur][0];
        const u32 knxa = 0, knxb = 0;
        (void)danext; (void)dbnext; (void)lbw; (void)knxa; (void)knxb;
        DO_TILE(0, 0, 0, 0, VMW2, VMW0, VMNOP, VMNOP);
    }

    const int col0 = n0 + wc * 64;
    const int row0 = m0 + wr * 128;
    float bcol[4];
#pragma unroll
    for (int nf = 0; nf < 4; ++nf) bcol[nf] = bias[col0 + nf * 16 + lr];
#pragma unroll
    for (int mf = 0; mf < 8; ++mf) {
#pragma unroll
        for (int r = 0; r < 4; ++r) {
            const int row = row0 + mf * 16 + kq * 4 + r;
            float nrm = 0.f;
#pragma unroll
            for (int nf = 0; nf < 4; ++nf) {
                float v = acc[mf][nf][r] + bcol[nf];
                C[(size_t)row * 1024 + col0 + nf * 16 + lr] = f2bf(v);
                nrm += v * v;
            }
#pragma unroll
            for (int off = 1; off < 16; off <<= 1) nrm += __shfl_xor(nrm, off, 64);
            if (lr == 0) atomicAdd(&wgn2[row], nrm);
        }
    }
}

// ================= GEMM2: part[z] = attn_bf @ W_mlp^T =================
// A bf16 dbuf (2x32KB) via gll16; B f32 SINGLE buffer (64KB) via gll16 with
// in-place half rotation; cvt f32->bf16 on the LDS->reg read (v_cvt_pk).
// Slots/tile (12): ph0 Ah0x2 | ph1 Br0x4 | ph2 Ah1x2+Br1x4.
// Waits: end-ph0 vmcnt(2) [retires prev ph2's 6]; end-ph3 vmcnt(6) [retires ph0+ph1].
// B granule XOR swizzle: g ^= (row&7)<<1, SAME involution on stage-source and read.
#define LDB(FR, RROW, H)                                                      \
  do {                                                                        \
    const int xr = ((RROW) & 7) << 1;                                         \
    const int gb = (H) * 8 + kq * 2;                                          \
    const float* prow = lbB + (RROW) * 64;                                    \
    f32x4 g0 = *(const f32x4*)(prow + ((gb ^ xr) << 2));                      \
    f32x4 g1 = *(const f32x4*)(prow + (((gb + 1) ^ xr) << 2));                \
    union { u32 w[4]; short8 s; } uu;                                         \
    uu.w[0] = cvtpk(g0.x, g0.y); uu.w[1] = cvtpk(g0.z, g0.w);                 \
    uu.w[2] = cvtpk(g1.x, g1.y); uu.w[3] = cvtpk(g1.z, g1.w);                 \
    FR = uu.s;                                                                \
  } while (0)

#define GT2F(ISS, W0X, W3X)                                                   \
  do {                                                                        \
    short8 Af[4][2], Bf0[2][2], Bf1[2][2];                                    \
    /* ph0: rd A-h0 + cvt-rd B rows 0-127; issue Ah0(T+1) */                  \
    _Pragma("unroll") for (int m = 0; m < 4; ++m) {                           \
      Af[m][0] = *(const short8*)(la + rpA[m] + sw0);                         \
      Af[m][1] = *(const short8*)(la + rpA[m] + sw1);                         \
    }                                                                         \
    _Pragma("unroll") for (int n = 0; n < 2; ++n) {                           \
      LDB(Bf0[n][0], rpBr[n], 0);                                             \
      LDB(Bf0[n][1], rpBr[n], 1);                                             \
    }                                                                         \
    if (ISS) { gll16(AG + (saO00 + knxa), danext + ldst);                     \
               gll16(AG + (saO01 + knxa), danext + 4096 + ldst); }            \
    SBAR(); SCHED0();                                                         \
    __builtin_amdgcn_s_setprio(1);                                            \
    _Pragma("unroll") for (int k = 0; k < 2; ++k)                             \
      _Pragma("unroll") for (int m = 0; m < 4; ++m)                           \
        _Pragma("unroll") for (int n = 0; n < 2; ++n)                         \
          acc[m][n] = MFMA16(Af[m][k], Bf0[n][k], acc[m][n]);                 \
    __builtin_amdgcn_s_setprio(0); SCHED0(); W0X; SBAR();                     \
    /* ph1: cvt-rd B rows 128-255; issue Br0(T+1) in place */                 \
    _Pragma("unroll") for (int n = 0; n < 2; ++n) {                           \
      LDB(Bf1[n][0], rpBr[n + 2], 0);                                         \
      LDB(Bf1[n][1], rpBr[n + 2], 1);                                         \
    }                                                                         \
    if (ISS) {                                                                \
      _Pragma("unroll") for (int r = 0; r < 4; ++r)                           \
        gll16(BGf + (bsrc[r] + knxbB), lbB + r * 2048 + wave * 256);          \
    }                                                                         \
    SBAR(); SCHED0();                                                         \
    __builtin_amdgcn_s_setprio(1);                                            \
    _Pragma("unroll") for (int k = 0; k < 2; ++k)                             \
      _Pragma("unroll") for (int m = 0; m < 4; ++m)                           \
        _Pragma("unroll") for (int n = 0; n < 2; ++n)                         \
          acc[m][n + 2] = MFMA16(Af[m][k], Bf1[n][k], acc[m][n + 2]);         \
    __builtin_amdgcn_s_setprio(0); SCHED0(); SBAR();                          \
    /* ph2: rd A-h1; issue Ah1(T+1) + Br1(T+1) in place */                    \
    _Pragma("unroll") for (int m = 0; m < 4; ++m) {                           \
      Af[m][0] = *(const short8*)(la + rpA[m + 4] + sw0);                     \
      Af[m][1] = *(const short8*)(la + rpA[m + 4] + sw1);                     \
    }                                                                         \
    if (ISS) {                                                                \
      gll16(AG + (saO10 + knxa), danext + 8192 + ldst);                       \
      gll16(AG + (saO11 + knxa), danext + 8192 + 4096 + ldst);                \
      _Pragma("unroll") for (int r = 4; r < 8; ++r)                           \
        gll16(BGf + (bsrc[r] + knxbB), lbB + r * 2048 + wave * 256);          \
    }                                                                         \
    SBAR(); SCHED0();                                                         \
    __builtin_amdgcn_s_setprio(1);                                            \
    _Pragma("unroll") for (int k = 0; k < 2; ++k)                             \
      _Pragma("unroll") for (int m = 0; m < 4; ++m)                           \
        _Pragma("unroll") for (int n = 0; n < 2; ++n)                         \
          acc[m + 4][n] = MFMA16(Af[m][k], Bf0[n][k], acc[m + 4][n]);         \
    /* ph3 (merged): q3 pure-reg */                                           \
    _Pragma("unroll") for (int k = 0; k < 2; ++k)                             \
      _Pragma("unroll") for (int m = 0; m < 4; ++m)                           \
        _Pragma("unroll") for (int n = 0; n < 2; ++n)                         \
          acc[m + 4][n + 2] = MFMA16(Af[m][k], Bf1[n][k], acc[m + 4][n + 2]); \
    __builtin_amdgcn_s_setprio(0); SCHED0(); W3X; SBAR();                     \
  } while (0)

__global__ __launch_bounds__(512, 2) void k_gemm2_f(const u16* __restrict__ AG,
                                                    const float* __restrict__ BGf,
                                                    u16* __restrict__ part) {
    __shared__ __align__(16) u16 LsA[2][16384];   // 64 KB
    __shared__ __align__(16) float LsBf[16384];   // 64 KB (single buffer)
    const int K = 16384, NT = 64;
    const int lin = blockIdx.x;
    const int w = (lin & 7) * 32 + (lin >> 3);
    const int m0 = (w & 3) * 256;
    const int z = (w >> 2) & 3;
    const int n0 = (w >> 4) * 256;
    const int kbeg = z * 4096;

    const int tid = threadIdx.x, wave = tid >> 6, lane = tid & 63;
    const int lr = lane & 15, kq = lane >> 4;
    const int wr = wave >> 2, wc = wave & 3;

    // A staging (bf16, as GEMM1)
    const int trow = tid >> 3;
    const u32 swsrc = (u32)(((tid & 7) ^ (trow & 7)) * 8);
    const u32 saO00 = (u32)(m0 + 0 + trow) * (u32)K + (u32)kbeg + swsrc;
    const u32 saO01 = (u32)(m0 + 128 + trow) * (u32)K + (u32)kbeg + swsrc;
    const u32 saO10 = (u32)(m0 + 64 + trow) * (u32)K + (u32)kbeg + swsrc;
    const u32 saO11 = (u32)(m0 + 192 + trow) * (u32)K + (u32)kbeg + swsrc;
    const u32 ldst = (u32)wave * 512;

    // B f32 staging: round r covers LDS rows r*32..r*32+31; thread (t2,g)
    const int t2 = tid >> 4;
    const int gpos = tid & 15;
    const u32 gs = (u32)(gpos ^ ((t2 & 7) << 1));
    u32 bsrc[8];
#pragma unroll
    for (int r = 0; r < 8; ++r) {
        const int nrow = n0 + (r & 3) * 64 + ((r >> 2) & 1) * 32 +
                         ((t2 >> 4) & 1) * 16 + (t2 & 15);
        bsrc[r] = (u32)nrow * (u32)K + (u32)kbeg + gs * 4;
    }
    float* lbB = &LsBf[0];

    int rpA[8], rpBr[4];
#pragma unroll
    for (int mf = 0; mf < 8; ++mf)
        rpA[mf] = ((mf >> 2) * 128 + wr * 64 + (mf & 3) * 16 + lr) << 6;
#pragma unroll
    for (int nf = 0; nf < 4; ++nf)
        rpBr[nf] = (nf >> 1) * 128 + wc * 32 + (nf & 1) * 16 + lr;
    const int sw0 = ((0 + kq) ^ (lr & 7)) * 8;
    const int sw1 = ((4 + kq) ^ (lr & 7)) * 8;

    f32x4 acc[8][4] = {};

    // prologue: full tile 0 (A 4 + B 8), drain
    {
        gll16(AG + saO00, &LsA[0][0] + ldst);
        gll16(AG + saO01, &LsA[0][0] + 4096 + ldst);
        gll16(AG + saO10, &LsA[0][0] + 8192 + ldst);
        gll16(AG + saO11, &LsA[0][0] + 8192 + 4096 + ldst);
#pragma unroll
        for (int r = 0; r < 8; ++r)
            gll16(BGf + bsrc[r], lbB + r * 2048 + wave * 256);
        VMW0; SBAR();
    }

    int cur = 0;
    for (int T = 0; T < NT - 1; ++T) {
        const u16* la = &LsA[cur][0];
        u16* danext = &LsA[cur ^ 1][0];
        const u32 knxa = (u32)(T + 1) * 64;
        const u32 knxbB = (u32)(T + 1) * 64;
        if (T == 0) {
            GT2F(1, VMNOP, VMW6);   // nothing older outstanding at ph0-end
        } else {
            GT2F(1, VMW2, VMW6);
        }
        cur ^= 1;
    }
    {   // last tile: no issues; ph0-end must retire ALL prior (Ah1+Br1 of this tile)
        const u16* la = &LsA[cur][0];
        u16* danext = &LsA[cur ^ 1][0];
        const u32 knxa = 0, knxbB = 0;
        (void)danext; (void)knxa; (void)knxbB;
        GT2F(0, VMW0, VMNOP);
    }

    u16* po = part + (size_t)z * 4194304ull;
    const int col0 = n0 + wc * 64;
    const int row0 = m0 + wr * 128;
#pragma unroll
    for (int mf = 0; mf < 8; ++mf)
#pragma unroll
        for (int r = 0; r < 4; ++r) {
            const int row = row0 + mf * 16 + kq * 4 + r;
#pragma unroll
            for (int nf = 0; nf < 4; ++nf)
                po[(size_t)row * 4096 + col0 + nf * 16 + lr] = f2bf(acc[mf][nf][r]);
        }
}

// ---------- merged per-batch graph algebra + attention readout ----------
__global__ __launch_bounds__(256) void k_batch_attn(const u16* xb,
                                                    const u16* __restrict__ wgb,
                                                    const float* __restrict__ xinv,
                                                    const float* __restrict__ wgn2,
                                                    const float* __restrict__ matrix,
                                                    const float* __restrict__ a_param,
                                                    float* __restrict__ e2_out,
                                                    float* __restrict__ m_out,
                                                    u16* attn_bf) {
    const int b = blockIdx.x, tid = threadIdx.x;
    const int wave = tid >> 6, lane = tid & 63;
    const int j = lane & 15, ig = (lane >> 4) * 4;

    __shared__ float qred[4][64][4];
    __shared__ float esm_l[16 * 17];
    __shared__ float fi_l[16 * 17];
    __shared__ float e2_l[16 * 17];
    __shared__ float m_l[256];
    __shared__ float as_l[256];
    __shared__ u16 xsh[16][256];

    {
        const size_t roff = (size_t)(b * 16 + j) * 1024 + (lane >> 4) * 8 + wave * 256;
        f32x4 acc0 = {}, acc1 = {};
#pragma unroll
        for (int kt = 0; kt < 256; kt += 64) {
            short8 xa0 = *(const short8*)(xb + roff + kt);
            short8 wa0 = *(const short8*)(wgb + roff + kt);
            short8 xa1 = *(const short8*)(xb + roff + kt + 32);
            short8 wa1 = *(const short8*)(wgb + roff + kt + 32);
            acc0 = __builtin_amdgcn_mfma_f32_16x16x32_bf16(xa0, wa0, acc0, 0, 0, 0);
            acc1 = __builtin_amdgcn_mfma_f32_16x16x32_bf16(xa1, wa1, acc1, 0, 0, 0);
        }
#pragma unroll
        for (int r = 0; r < 4; ++r) qred[wave][lane][r] = acc0[r] + acc1[r];
    }
    __syncthreads();

    if (tid < 64) {
        const int l = tid;
        const float inw = 1.0f / fmaxf(sqrtf(wgn2[b * 16 + j]), 1e-12f);
        const float boost = 1.0f + a_param[0];
        float e[4];
#pragma unroll
        for (int r = 0; r < 4; ++r) {
            const int i = ig + r;
            float v = (qred[0][l][r] + qred[1][l][r] + qred[2][l][r] + qred[3][l][r]) *
                      xinv[b * 16 + i] * inw;
            if (i == j) v *= boost;
            e[r] = v;
            as_l[i * 16 + j] = v;
        }
        float mx = fmaxf(fmaxf(e[0], e[1]), fmaxf(e[2], e[3]));
        mx = fmaxf(mx, __shfl_xor(mx, 16, 64));
        mx = fmaxf(mx, __shfl_xor(mx, 32, 64));
        float p[4], s = 0.f;
#pragma unroll
        for (int r = 0; r < 4; ++r) { p[r] = __expf(e[r] - mx); s += p[r]; }
        s += __shfl_xor(s, 16, 64);
        s += __shfl_xor(s, 32, 64);
        const float invs = 1.0f / s;
#pragma unroll
        for (int r = 0; r < 4; ++r) esm_l[(ig + r) * 17 + j] = p[r] * invs;
        const f32x4 mv = *(const f32x4*)(matrix + (size_t)b * 256 + 4 * l);
        *(f32x4*)(m_l + 4 * l) = mv;
        *(f32x4*)(m_out + (size_t)b * 256 + 4 * l) = mv;
    }
    __syncthreads();
    if (tid < 64) {
        float fi[4] = {0, 0, 0, 0};
#pragma unroll
        for (int t = 0; t < 16; ++t) {
            const float mk = m_l[t * 16 + j];
#pragma unroll
            for (int r = 0; r < 4; ++r) fi[r] += esm_l[(ig + r) * 17 + t] * mk;
        }
#pragma unroll
        for (int r = 0; r < 4; ++r) fi_l[(ig + r) * 17 + j] = fi[r];
    }
    __syncthreads();
    if (tid < 64) {
        float e2v[4] = {0, 0, 0, 0};
#pragma unroll
        for (int kk = 0; kk < 16; ++kk) {
            const float wgt = esm_l[j * 17 + kk] * m_l[kk * 16 + kk];
#pragma unroll
            for (int r = 0; r < 4; ++r) e2v[r] += fi_l[(ig + r) * 17 + kk] * wgt;
        }
#pragma unroll
        for (int r = 0; r < 4; ++r) e2_l[(ig + r) * 17 + j] = e2v[r];
    }
    __syncthreads();
    if (tid < 64) {
#pragma unroll
        for (int r = 0; r < 4; ++r) {
            const int i = ig + r;
            e2_out[(size_t)b * 256 + i * 16 + j] =
                0.5f * (e2_l[i * 17 + j] + e2_l[j * 17 + i]);
        }
    }

    const int srow = tid >> 4;
    const int scol = (tid & 15) * 16;
    for (int ch = 0; ch < 4; ++ch) {
        __syncthreads();
        const u16* src = xb + ((size_t)b * 16 + srow) * 1024 + ch * 256 + scol;
        *(short8*)&xsh[srow][scol] = *(const short8*)src;
        *(short8*)&xsh[srow][scol + 8] = *(const short8*)(src + 8);
        __syncthreads();
        float accv[16] = {};
#pragma unroll
        for (int jj = 0; jj < 16; ++jj) {
            const float xv = bf2f(xsh[jj][tid]);
#pragma unroll
            for (int i = 0; i < 16; ++i) accv[i] = fmaf(as_l[jj * 16 + i], xv, accv[i]);
        }
#pragma unroll
        for (int i = 0; i < 16; ++i)
            attn_bf[((size_t)b * 16 + i) * 1024 + ch * 256 + tid] = f2bf(ftanh(accv[i]));
    }
}

// ---------- broadcast: out[b, rep, :] = sum_z part[z][b,:] + b_mlp ----------
__global__ __launch_bounds__(256) void k_bcast(const u16* __restrict__ p,
                                               const float* __restrict__ bias,
                                               float* __restrict__ out) {
    const size_t i = (size_t)blockIdx.x * 256 + threadIdx.x;
    const int o4 = (int)(i & 1023);
    const int b = (int)(i >> 14);
    const size_t src = (size_t)b * 4096 + (size_t)o4 * 4;
    f32x4 r = *(const f32x4*)(bias + (size_t)o4 * 4);
#pragma unroll
    for (int z = 0; z < 4; ++z) {
        us4 v = *(const us4*)(p + (size_t)z * 4194304ull + src);
        r.x += bf2f(v.x); r.y += bf2f(v.y); r.z += bf2f(v.z); r.w += bf2f(v.w);
    }
    *(f32x4*)(out + i * 4) = r;
}

extern "C" void kernel_launch(void* const* d_in, const int* in_sizes, int n_in,
                              void* d_out, int out_size, void* d_ws, size_t ws_size,
                              hipStream_t stream) {
    const float* x      = (const float*)d_in[0];
    const float* matrix = (const float*)d_in[1];
    const float* W1     = (const float*)d_in[2];
    const float* b1     = (const float*)d_in[3];
    const float* W_mlp  = (const float*)d_in[4];
    const float* b_mlp  = (const float*)d_in[5];
    const float* a_par  = (const float*)d_in[6];
    float* out = (float*)d_out;

    char* ws = (char*)d_ws;
    size_t off = 0;
    auto alloc = [&](size_t bytes) {
        char* p = ws + off;
        off += (bytes + 255) & ~(size_t)255;
        return p;
    };
    u16*   x_bf  = (u16*)alloc(16384ull * 1024 * 2);    // reused as attn_bf
    u16*   wg_bf = (u16*)alloc(16384ull * 1024 * 2);    // reused as GEMM2 bf16 partials
    u16*   w1_bf = (u16*)alloc(1024ull * 1024 * 2);
    float* xinv  = (float*)alloc(16384ull * 4);
    float* wgn2  = (float*)alloc(16384ull * 4);
    u16*   attn_bf = x_bf;
    u16*   part    = wg_bf;
    float* e2_out = out + 67108864ull;
    float* m_out  = out + 67371008ull;

    hipMemsetAsync(wgn2, 0, 16384 * 4, stream);
    k_cvt_x<<<17408, 256, 0, stream>>>(x, x_bf, xinv, W1, w1_bf);
    k_gemm1_8ph<<<256, 512, 0, stream>>>(x_bf, w1_bf, b1, wg_bf, wgn2);
    k_batch_attn<<<1024, 256, 0, stream>>>(x_bf, wg_bf, xinv, wgn2, matrix, a_par,
                                           e2_out, m_out, attn_bf);
    k_gemm2_f<<<256, 512, 0, stream>>>(attn_bf, W_mlp, part);
    k_bcast<<<65536, 256, 0, stream>>>(part, b_mlp, out);
}